// Round 1
// baseline (63.742 us; speedup 1.0000x reference)
//
#include <hip/hip_runtime.h>

typedef unsigned short u16;
typedef __bf16 bf16;
typedef __bf16 bf16x8 __attribute__((ext_vector_type(8)));
typedef float f32x4 __attribute__((ext_vector_type(4)));

// Problem constants: B=4, S=2048, DIM=1024, DK=DV=128, rows = B*S = 8192.

__device__ __forceinline__ void gl_lds16(const void* g, void* l) {
  __builtin_amdgcn_global_load_lds(
      (const __attribute__((address_space(1))) void*)g,
      (__attribute__((address_space(3))) void*)l, 16, 0, 0);
}

__device__ __forceinline__ u16 bfbits(float f) {
  return __builtin_bit_cast(u16, (bf16)f);
}

// ---------------- W transpose + convert: Wt[m][n][k] = bf16(W_m[k][n]) -------
__global__ void wprep_kernel(const float* __restrict__ Wq, const float* __restrict__ Wk,
                             const float* __restrict__ Wv, u16* __restrict__ Wt) {
  int idx = blockIdx.x * 256 + threadIdx.x;   // 0..393215
  int m = idx >> 17;
  int rem = idx & 131071;                     // = k*128 + n
  int k = rem >> 7, n = rem & 127;
  const float* W = (m == 0) ? Wq : (m == 1) ? Wk : Wv;
  Wt[(size_t)m * 131072 + (size_t)n * 1024 + k] = bfbits(W[rem]);
}

// ---------------- QKV projection GEMM ---------------------------------------
// grid (128, 3); block 256 (4 waves, 2x2). Tile 64x128, BK=64.
// sx: [64][68] f32 (pad 4 f32 = 16B per row -> 2-way bank alias on frag reads)
// sw: [128][72] bf16 (pad 8 bf16 = 16B)
__global__ __launch_bounds__(256) void qkv_gemm(
    const float* __restrict__ x, const u16* __restrict__ Wt,
    const float* __restrict__ bq, const float* __restrict__ bk, const float* __restrict__ bv,
    u16* __restrict__ qb, u16* __restrict__ kb, u16* __restrict__ vt)
{
  __shared__ __attribute__((aligned(16))) float sx[64 * 68];
  __shared__ __attribute__((aligned(16))) u16   sw[128 * 72];
  const int tid = threadIdx.x, wid = tid >> 6, lane = tid & 63;
  const int m = blockIdx.y;
  const int row0 = blockIdx.x * 64;
  const u16* W = Wt + (size_t)m * 131072;
  const int wr = wid >> 1, wc = wid & 1;

  // staging descriptors (pre-skewed global src; linear LDS dest)
  const float* xsp[5]; char* xdst[5];
  const u16*   wsp[5]; char* wdst[5];
#pragma unroll
  for (int i = 0; i < 5; ++i) {
    int fc = i * 256 + tid;
    { int r = fc / 17, cc = fc % 17; if (r > 63) r = 63;       // 17 chunks of 16B per 68-f32 row
      xsp[i]  = x + (size_t)(row0 + r) * 1024 + (cc < 16 ? cc * 4 : 0);
      xdst[i] = (char*)sx + (size_t)(i * 256 + wid * 64) * 16; }
    { int r = fc / 9, cc = fc % 9; if (r > 127) r = 127;       // 9 chunks per 72-bf16 row
      wsp[i]  = W + (size_t)r * 1024 + (cc < 8 ? cc * 8 : 0);
      wdst[i] = (char*)sw + (size_t)(i * 256 + wid * 64) * 16; }
  }

  f32x4 acc[2][4] = {};
  for (int kt = 0; kt < 16; ++kt) {
    const int k0 = kt * 64;
#pragma unroll
    for (int i = 0; i < 5; ++i) {
      if (i < 4 || tid < 64)  gl_lds16(xsp[i] + k0, xdst[i]);   // 1088 chunks
      if (i < 4 || tid < 128) gl_lds16(wsp[i] + k0, wdst[i]);   // 1152 chunks
    }
    asm volatile("s_waitcnt vmcnt(0)" ::: "memory");
    __syncthreads();
#pragma unroll
    for (int ks = 0; ks < 2; ++ks) {
      bf16x8 af[2]; bf16x8 bfr[4];
#pragma unroll
      for (int mr = 0; mr < 2; ++mr) {
        const float* p = &sx[(wr * 32 + mr * 16 + (lane & 15)) * 68 + ks * 32 + (lane >> 4) * 8];
        f32x4 lo = *(const f32x4*)p, hi = *(const f32x4*)(p + 4);
        bf16x8 v;
        v[0] = (bf16)lo[0]; v[1] = (bf16)lo[1]; v[2] = (bf16)lo[2]; v[3] = (bf16)lo[3];
        v[4] = (bf16)hi[0]; v[5] = (bf16)hi[1]; v[6] = (bf16)hi[2]; v[7] = (bf16)hi[3];
        af[mr] = v;
      }
#pragma unroll
      for (int nr = 0; nr < 4; ++nr)
        bfr[nr] = *(const bf16x8*)&sw[(wc * 64 + nr * 16 + (lane & 15)) * 72 + ks * 32 + (lane >> 4) * 8];
#pragma unroll
      for (int mr = 0; mr < 2; ++mr)
#pragma unroll
        for (int nr = 0; nr < 4; ++nr)
          acc[mr][nr] = __builtin_amdgcn_mfma_f32_16x16x32_bf16(af[mr], bfr[nr], acc[mr][nr], 0, 0, 0);
    }
    __syncthreads();
  }

  const float* bias = (m == 0) ? bq : (m == 1) ? bk : bv;
  u16* qk = (m == 0) ? qb : kb;
#pragma unroll
  for (int mr = 0; mr < 2; ++mr) {
#pragma unroll
    for (int nr = 0; nr < 4; ++nr) {
      int col = wc * 64 + nr * 16 + (lane & 15);
      float bc = bias[col];
      int grow = row0 + wr * 32 + mr * 16 + (lane >> 4) * 4;
      if (m == 2) {
        // store V transposed: vt[b][d=col][s], 4 consecutive s per lane -> 8B store
        int b = grow >> 11, s = grow & 2047;
        ushort4 u;
        u.x = bfbits(acc[mr][nr][0] + bc);
        u.y = bfbits(acc[mr][nr][1] + bc);
        u.z = bfbits(acc[mr][nr][2] + bc);
        u.w = bfbits(acc[mr][nr][3] + bc);
        *(ushort4*)&vt[(size_t)b * 262144 + (size_t)col * 2048 + s] = u;
      } else {
#pragma unroll
        for (int r = 0; r < 4; ++r)
          qk[(size_t)(grow + r) * 128 + col] = bfbits(acc[mr][nr][r] + bc);
      }
    }
  }
}

// ---------------- Flash attention with 4-way KV split -----------------------
// grid (32 q-tiles, 4 splits, 4 batch); block 256 (4 waves x 16 q-rows).
// sk: [64][136] bf16 K-tile (pad 16B), sv: [128][72] bf16 V^T-tile, sp: P roundtrip.
__global__ __launch_bounds__(256) void attn_kernel(
    const u16* __restrict__ qb, const u16* __restrict__ kb, const u16* __restrict__ vt,
    float* __restrict__ Opart, float* __restrict__ Mws, float* __restrict__ Lws)
{
  __shared__ __attribute__((aligned(16))) u16 sk[64 * 136];
  __shared__ __attribute__((aligned(16))) u16 sv[128 * 72];
  __shared__ __attribute__((aligned(16))) u16 sp[64 * 72];
  const int tid = threadIdx.x, wid = tid >> 6, lane = tid & 63;
  const int qt = blockIdx.x, split = blockIdx.y, b = blockIdx.z;
  const size_t qg0 = (size_t)b * 2048 + qt * 64 + wid * 16;

  // Q fragments held in registers (A-operand: row = lane&15, k = (lane>>4)*8..+8)
  bf16x8 qf[4];
#pragma unroll
  for (int kg = 0; kg < 4; ++kg)
    qf[kg] = *(const bf16x8*)&qb[(qg0 + (lane & 15)) * 128 + kg * 32 + (lane >> 4) * 8];

  const u16* ksp[5]; char* kdst[5];
  const u16* vsp[5]; char* vdst[5];
#pragma unroll
  for (int i = 0; i < 5; ++i) {
    int fc = i * 256 + tid;
    { int r = fc / 17, cc = fc % 17; if (r > 63) r = 63;      // 136 bf16 = 17 x 16B
      ksp[i]  = kb + ((size_t)b * 2048 + split * 512 + r) * 128 + (cc < 16 ? cc * 8 : 0);
      kdst[i] = (char*)sk + (size_t)(i * 256 + wid * 64) * 16; }
    { int r = fc / 9, cc = fc % 9; if (r > 127) r = 127;      // 72 bf16 = 9 x 16B
      vsp[i]  = vt + (size_t)b * 262144 + (size_t)r * 2048 + split * 512 + (cc < 8 ? cc * 8 : 0);
      vdst[i] = (char*)sv + (size_t)(i * 256 + wid * 64) * 16; }
  }

  float mrow[4] = {-INFINITY, -INFINITY, -INFINITY, -INFINITY};
  float lrow[4] = {0.f, 0.f, 0.f, 0.f};
  f32x4 acc_o[8] = {};
  const float scale = 0.08838834764831845f;   // 128^-0.5

  for (int t = 0; t < 8; ++t) {
#pragma unroll
    for (int i = 0; i < 5; ++i) {
      if (i < 4 || tid < 64)  gl_lds16(ksp[i] + (size_t)t * 8192, kdst[i]);
      if (i < 4 || tid < 128) gl_lds16(vsp[i] + t * 64, vdst[i]);
    }
    asm volatile("s_waitcnt vmcnt(0)" ::: "memory");
    __syncthreads();

    // S = Q K^T  (S[qrow][j]; C layout: col j = lane&15 (+16*jg), row = (lane>>4)*4+reg)
    f32x4 s[4] = {};
#pragma unroll
    for (int kg = 0; kg < 4; ++kg)
#pragma unroll
      for (int jg = 0; jg < 4; ++jg) {
        bf16x8 kf = *(const bf16x8*)&sk[(jg * 16 + (lane & 15)) * 136 + kg * 32 + (lane >> 4) * 8];
        s[jg] = __builtin_amdgcn_mfma_f32_16x16x32_bf16(qf[kg], kf, s[jg], 0, 0, 0);
      }

    // online softmax per q-row (row-reduce across the 16 j-lanes)
    float al[4]; float pr[4][4];
#pragma unroll
    for (int r = 0; r < 4; ++r) {
      float s0 = s[0][r] * scale, s1 = s[1][r] * scale, s2 = s[2][r] * scale, s3 = s[3][r] * scale;
      float tm = fmaxf(fmaxf(s0, s1), fmaxf(s2, s3));
      tm = fmaxf(tm, __shfl_xor(tm, 1));
      tm = fmaxf(tm, __shfl_xor(tm, 2));
      tm = fmaxf(tm, __shfl_xor(tm, 4));
      tm = fmaxf(tm, __shfl_xor(tm, 8));
      float mn = fmaxf(mrow[r], tm);
      float p0 = __expf(s0 - mn), p1 = __expf(s1 - mn), p2 = __expf(s2 - mn), p3 = __expf(s3 - mn);
      pr[0][r] = p0; pr[1][r] = p1; pr[2][r] = p2; pr[3][r] = p3;
      float rs = p0 + p1 + p2 + p3;
      rs += __shfl_xor(rs, 1);
      rs += __shfl_xor(rs, 2);
      rs += __shfl_xor(rs, 4);
      rs += __shfl_xor(rs, 8);
      float a = __expf(mrow[r] - mn);
      lrow[r] = lrow[r] * a + rs;
      mrow[r] = mn;
      al[r] = a;
    }
#pragma unroll
    for (int dg = 0; dg < 8; ++dg) {
      acc_o[dg][0] *= al[0]; acc_o[dg][1] *= al[1];
      acc_o[dg][2] *= al[2]; acc_o[dg][3] *= al[3];
    }

    // P: C-layout -> A-layout via wave-private LDS roundtrip (padded rows)
#pragma unroll
    for (int jg = 0; jg < 4; ++jg)
#pragma unroll
      for (int r = 0; r < 4; ++r)
        sp[(wid * 16 + (lane >> 4) * 4 + r) * 72 + jg * 16 + (lane & 15)] = bfbits(pr[jg][r]);
    asm volatile("s_waitcnt lgkmcnt(0)" ::: "memory");
    bf16x8 pf[2];
#pragma unroll
    for (int k2 = 0; k2 < 2; ++k2)
      pf[k2] = *(const bf16x8*)&sp[(wid * 16 + (lane & 15)) * 72 + k2 * 32 + (lane >> 4) * 8];

    // O += P V  (B-operand from V^T tile: contiguous j per lane)
#pragma unroll
    for (int dg = 0; dg < 8; ++dg)
#pragma unroll
      for (int k2 = 0; k2 < 2; ++k2) {
        bf16x8 vf = *(const bf16x8*)&sv[(dg * 16 + (lane & 15)) * 72 + k2 * 32 + (lane >> 4) * 8];
        acc_o[dg] = __builtin_amdgcn_mfma_f32_16x16x32_bf16(pf[k2], vf, acc_o[dg], 0, 0, 0);
      }
    __syncthreads();
  }

  const size_t prow = (size_t)split * 8192 + qg0;
#pragma unroll
  for (int dg = 0; dg < 8; ++dg)
#pragma unroll
    for (int r = 0; r < 4; ++r)
      Opart[(prow + (lane >> 4) * 4 + r) * 128 + dg * 16 + (lane & 15)] = acc_o[dg][r];
  if ((lane & 15) == 0) {
#pragma unroll
    for (int r = 0; r < 4; ++r) {
      Mws[prow + (lane >> 4) * 4 + r] = mrow[r];
      Lws[prow + (lane >> 4) * 4 + r] = lrow[r];
    }
  }
}

// ---------------- combine the 4 KV-split partials ---------------------------
__global__ void combine_kernel(const float* __restrict__ Opart, const float* __restrict__ Mws,
                               const float* __restrict__ Lws, float* __restrict__ out)
{
  int idx = blockIdx.x * 256 + threadIdx.x;   // 0..1048575
  int row = idx >> 7;
  float m0 = Mws[row], m1 = Mws[8192 + row], m2 = Mws[16384 + row], m3 = Mws[24576 + row];
  float ms = fmaxf(fmaxf(m0, m1), fmaxf(m2, m3));
  float w0 = __expf(m0 - ms), w1 = __expf(m1 - ms), w2 = __expf(m2 - ms), w3 = __expf(m3 - ms);
  float den = w0 * Lws[row] + w1 * Lws[8192 + row] + w2 * Lws[16384 + row] + w3 * Lws[24576 + row];
  float num = w0 * Opart[idx] + w1 * Opart[1048576 + idx]
            + w2 * Opart[2097152 + idx] + w3 * Opart[3145728 + idx];
  out[idx] = num / den;
}

// ---------------- launch ----------------------------------------------------
// Workspace layout (needs ~23.3 MB):
//   0      : qb   (8192x128 bf16, 2 MB)
//   2 MB   : kb   (2 MB)
//   4 MB   : vt   (V transposed per batch: [4][128][2048] bf16, 2 MB)
//   6 MB   : Wt   (3x[128][1024] bf16, 0.75 MB)
//   7 MB   : Opart ([4][8192][128] f32, 16 MB)
//   23 MB  : Mws  ([4][8192] f32, 128 KB)
//   23 MB+128 KB : Lws (128 KB)
extern "C" void kernel_launch(void* const* d_in, const int* in_sizes, int n_in,
                              void* d_out, int out_size, void* d_ws, size_t ws_size,
                              hipStream_t stream)
{
  (void)in_sizes; (void)n_in; (void)out_size; (void)ws_size;
  const float* x  = (const float*)d_in[0];
  const float* Wq = (const float*)d_in[1];
  const float* bq = (const float*)d_in[2];
  const float* Wk = (const float*)d_in[3];
  const float* bk = (const float*)d_in[4];
  const float* Wv = (const float*)d_in[5];
  const float* bv = (const float*)d_in[6];
  char* ws = (char*)d_ws;
  u16* qbuf   = (u16*)(ws);
  u16* kbuf   = (u16*)(ws + (2u << 20));
  u16* vtbuf  = (u16*)(ws + (4u << 20));
  u16* Wt     = (u16*)(ws + (6u << 20));
  float* Opart = (float*)(ws + (7u << 20));
  float* Mws   = (float*)(ws + (23u << 20));
  float* Lws   = (float*)(ws + (23u << 20) + (128u << 10));

  wprep_kernel<<<1536, 256, 0, stream>>>(Wq, Wk, Wv, Wt);
  qkv_gemm<<<dim3(128, 3), 256, 0, stream>>>(x, Wt, bq, bk, bv, qbuf, kbuf, vtbuf);
  attn_kernel<<<dim3(32, 4, 4), 256, 0, stream>>>(qbuf, kbuf, vtbuf, Opart, Mws, Lws);
  combine_kernel<<<4096, 256, 0, stream>>>(Opart, Mws, Lws, (float*)d_out);
}